// Round 1
// baseline (265.562 us; speedup 1.0000x reference)
//
#include <hip/hip_runtime.h>

// Problem constants (fixed by setup_inputs)
#define DD 160
#define HH 192
#define WW 160
constexpr int DHW = DD * HH * WW;

typedef float vfloat4 __attribute__((ext_vector_type(4)));  // native vector for NT builtins

__global__ __launch_bounds__(256) void st_fused_kernel(
    const float* __restrict__ src,    // [1,1,D,H,W]
    const float* __restrict__ flow1,  // [1,3,D,H,W]
    const float* __restrict__ flow2,  // [1,3,D,H,W]
    const float* __restrict__ prf,    // scalar range_flow
    float* __restrict__ out)          // [DHW deform | 3*DHW out_flow]
{
    // ---- XCD-aware bijective block swizzle: 4800 blocks = 8 XCDs x 600.
    // Each XCD then owns a contiguous z-slab; its src gather footprint
    // (~2.5 MB + jitter borders) fits the 4 MiB per-XCD L2.
    int bid = (int)blockIdx.x;
    int nb  = (int)gridDim.x;
    int swz = bid;
    if ((nb & 7) == 0) {                  // bijective only when nb % 8 == 0
        int chunk = nb >> 3;
        swz = (bid & 7) * chunk + (bid >> 3);
    }
    int tid  = swz * 256 + (int)threadIdx.x;
    int idx0 = tid * 4;                   // 4 consecutive x-voxels per thread
    if (idx0 >= DHW) return;              // DHW % 1024 == 0, so full groups only

    const float rf = prf[0];

    int xb = idx0 % WW;                   // group never crosses a row (WW%4==0)
    int t  = idx0 / WW;
    int y  = t % HH;
    int z  = t / HH;

    // flow2 is streamed exactly once -> nontemporal so it doesn't evict the
    // hot src slab from L2.
    const vfloat4 f2zv = __builtin_nontemporal_load((const vfloat4*)(flow2 + idx0));
    const vfloat4 f2yv = __builtin_nontemporal_load((const vfloat4*)(flow2 + idx0 + DHW));
    const vfloat4 f2xv = __builtin_nontemporal_load((const vfloat4*)(flow2 + idx0 + 2 * DHW));

    // ---- phase 1: first grid_sample (flow1 at grid2 treated as NORMALIZED
    // coords). In-range only in a tiny corner slab -> branch is rare and
    // wave-uniform almost everywhere. Kept OUTSIDE the main gather so it
    // can't fence the 32-load batch below.
    float fwz[4], fwy[4], fwx[4];
    #pragma unroll
    for (int j = 0; j < 4; ++j) {
        fwz[j] = 0.0f; fwy[j] = 0.0f; fwx[j] = 0.0f;
        int x = xb + j;
        float g2z = (float)z + f2zv[j] * rf;
        float g2y = (float)y + f2yv[j] * rf;
        float g2x = (float)x + f2xv[j] * rf;
        float iz = ((g2z + 1.0f) * (float)DD - 1.0f) * 0.5f;
        float iy = ((g2y + 1.0f) * (float)HH - 1.0f) * 0.5f;
        float ix = ((g2x + 1.0f) * (float)WW - 1.0f) * 0.5f;
        if (ix > -1.0f && ix < (float)WW &&
            iy > -1.0f && iy < (float)HH &&
            iz > -1.0f && iz < (float)DD) {
            float zf = floorf(iz), yf = floorf(iy), xf = floorf(ix);
            int z0 = (int)zf, y0 = (int)yf, x0 = (int)xf;
            float tz = iz - zf, ty = iy - yf, tx = ix - xf;
            #pragma unroll
            for (int dz = 0; dz < 2; ++dz) {
                int zc = z0 + dz;
                if (zc < 0 || zc >= DD) continue;
                float wz = dz ? tz : 1.0f - tz;
                #pragma unroll
                for (int dy = 0; dy < 2; ++dy) {
                    int yc = y0 + dy;
                    if (yc < 0 || yc >= HH) continue;
                    float wzy = wz * (dy ? ty : 1.0f - ty);
                    #pragma unroll
                    for (int dx = 0; dx < 2; ++dx) {
                        int xc = x0 + dx;
                        if (xc < 0 || xc >= WW) continue;
                        float w = wzy * (dx ? tx : 1.0f - tx);
                        int off = (zc * HH + yc) * WW + xc;
                        fwz[j] += w * flow1[off];
                        fwy[j] += w * flow1[off + DHW];
                        fwx[j] += w * flow1[off + 2 * DHW];
                    }
                }
            }
        }
    }

    // ---- phase 2: addressing + weights for ALL 4 points of the second
    // grid_sample (src at normalized(grid + out_flow*rf)).
    vfloat4 vofz, vofy, vofx;
    float wz[4][2], wy[4][2], wx[4][2];
    int   ro[4][2][2];                    // row offset per (dz,dy)
    int   xic[4][2];                      // clamped x index per dx

    #pragma unroll
    for (int j = 0; j < 4; ++j) {
        int x = xb + j;
        float ofz = fwz[j] + f2zv[j];
        float ofy = fwy[j] + f2yv[j];
        float ofx = fwx[j] + f2xv[j];
        vofz[j] = ofz; vofy[j] = ofy; vofx[j] = ofx;

        float nz = (float)z + ofz * rf;
        float ny = (float)y + ofy * rf;
        float nx = (float)x + ofx * rf;
        float cz = 2.0f * (nz / (float)(DD - 1) - 0.5f);
        float cy = 2.0f * (ny / (float)(HH - 1) - 0.5f);
        float cx = 2.0f * (nx / (float)(WW - 1) - 0.5f);
        float sz2 = ((cz + 1.0f) * (float)DD - 1.0f) * 0.5f;
        float sy2 = ((cy + 1.0f) * (float)HH - 1.0f) * 0.5f;
        float sx2 = ((cx + 1.0f) * (float)WW - 1.0f) * 0.5f;

        float zf = floorf(sz2), yf = floorf(sy2), xf = floorf(sx2);
        int z0 = (int)zf, y0 = (int)yf, x0 = (int)xf;
        float tz = sz2 - zf, ty = sy2 - yf, tx = sx2 - xf;

        wz[j][0] = 1.0f - tz; wz[j][1] = tz;
        wy[j][0] = 1.0f - ty; wy[j][1] = ty;
        wx[j][0] = 1.0f - tx; wx[j][1] = tx;

        int zi[2], yi[2];
        #pragma unroll
        for (int d = 0; d < 2; ++d) {
            int zc = z0 + d, yc = y0 + d, xc = x0 + d;
            if (zc < 0 || zc >= DD) wz[j][d] = 0.0f;
            if (yc < 0 || yc >= HH) wy[j][d] = 0.0f;
            if (xc < 0 || xc >= WW) wx[j][d] = 0.0f;
            zi[d]     = min(max(zc, 0), DD - 1);
            yi[d]     = min(max(yc, 0), HH - 1);
            xic[j][d] = min(max(xc, 0), WW - 1);
        }
        #pragma unroll
        for (int dz = 0; dz < 2; ++dz)
            #pragma unroll
            for (int dy = 0; dy < 2; ++dy)
                ro[j][dz][dy] = (zi[dz] * HH + yi[dy]) * WW;
    }

    // ---- phase 3: issue ALL 32 scattered loads back-to-back (independent),
    // so the wave keeps 32 vmem ops in flight instead of 8.
    float v[4][8];
    #pragma unroll
    for (int j = 0; j < 4; ++j)
        #pragma unroll
        for (int dz = 0; dz < 2; ++dz)
            #pragma unroll
            for (int dy = 0; dy < 2; ++dy)
                #pragma unroll
                for (int dx = 0; dx < 2; ++dx)
                    v[j][dz * 4 + dy * 2 + dx] = src[ro[j][dz][dy] + xic[j][dx]];

    // ---- phase 4: combine + store
    vfloat4 sval;
    #pragma unroll
    for (int j = 0; j < 4; ++j) {
        float acc = 0.0f;
        #pragma unroll
        for (int dz = 0; dz < 2; ++dz)
            #pragma unroll
            for (int dy = 0; dy < 2; ++dy)
                #pragma unroll
                for (int dx = 0; dx < 2; ++dx)
                    acc = fmaf(wz[j][dz] * wy[j][dy] * wx[j][dx],
                               v[j][dz * 4 + dy * 2 + dx], acc);
        sval[j] = acc;
    }

    // outputs: (deform [DHW], out_flow [3*DHW]) concatenated; NT stores —
    // never re-read, keep them out of L2 so the src gather set stays hot.
    __builtin_nontemporal_store(sval, (vfloat4*)(out + idx0));
    __builtin_nontemporal_store(vofz, (vfloat4*)(out + DHW + idx0));
    __builtin_nontemporal_store(vofy, (vfloat4*)(out + 2 * DHW + idx0));
    __builtin_nontemporal_store(vofx, (vfloat4*)(out + 3 * DHW + idx0));
}

extern "C" void kernel_launch(void* const* d_in, const int* in_sizes, int n_in,
                              void* d_out, int out_size, void* d_ws, size_t ws_size,
                              hipStream_t stream) {
    const float* src   = (const float*)d_in[0];
    const float* flow1 = (const float*)d_in[1];
    const float* flow2 = (const float*)d_in[2];
    // d_in[3] is the meshgrid `grid` — deterministic, computed analytically in-kernel.
    const float* prf   = (const float*)d_in[4];
    float* out = (float*)d_out;

    int threads_total = DHW / 4;
    int blocks = (threads_total + 255) / 256;   // 4800, divisible by 8
    st_fused_kernel<<<blocks, 256, 0, stream>>>(src, flow1, flow2, prf, out);
}

// Round 2
// 252.491 us; speedup vs baseline: 1.0518x; 1.0518x over previous
//
#include <hip/hip_runtime.h>

// Problem constants (fixed by setup_inputs)
#define DD 160
#define HH 192
#define WW 160
constexpr int DHW = DD * HH * WW;

typedef float vfloat4 __attribute__((ext_vector_type(4)));  // native vector for NT builtins
typedef float vfloat2 __attribute__((ext_vector_type(2)));

// 8-byte pair load with only 4-byte alignment guarantee. memcpy lets the
// backend emit global_load_dwordx2 (gfx9+ supports dword-aligned x2); if it
// ever splits, we're back to two scalar loads == status quo, no regression.
__device__ __forceinline__ vfloat2 load_pair(const float* __restrict__ p) {
    vfloat2 r;
    __builtin_memcpy(&r, p, 8);
    return r;
}

__global__ __launch_bounds__(256) void st_fused_kernel(
    const float* __restrict__ src,    // [1,1,D,H,W]
    const float* __restrict__ flow1,  // [1,3,D,H,W]
    const float* __restrict__ flow2,  // [1,3,D,H,W]
    const float* __restrict__ prf,    // scalar range_flow
    float* __restrict__ out)          // [DHW deform | 3*DHW out_flow]
{
    // XCD-aware bijective swizzle (4800 = 8 * 600): keeps each XCD's src
    // gather footprint (~2.5 MB slab) inside its 4 MiB L2. Halved FETCH_SIZE
    // in R1; kept to stay off the HBM roof as the TA floor drops.
    int bid = (int)blockIdx.x;
    int nb  = (int)gridDim.x;
    int swz = bid;
    if ((nb & 7) == 0) {
        int chunk = nb >> 3;
        swz = (bid & 7) * chunk + (bid >> 3);
    }
    int tid  = swz * 256 + (int)threadIdx.x;
    int idx0 = tid * 4;                   // 4 consecutive x-voxels per thread
    if (idx0 >= DHW) return;              // DHW % 1024 == 0

    const float rf = prf[0];

    int xb = idx0 % WW;                   // group never crosses a row (WW%4==0)
    int t  = idx0 / WW;
    int y  = t % HH;
    int z  = t / HH;

    // flow2 streamed once -> nontemporal, don't evict the hot src slab.
    const vfloat4 f2zv = __builtin_nontemporal_load((const vfloat4*)(flow2 + idx0));
    const vfloat4 f2yv = __builtin_nontemporal_load((const vfloat4*)(flow2 + idx0 + DHW));
    const vfloat4 f2xv = __builtin_nontemporal_load((const vfloat4*)(flow2 + idx0 + 2 * DHW));

    // ---- phase 1: first grid_sample (flow1 at grid2 treated as NORMALIZED
    // coords) — in-range only in a tiny corner slab; branch is rare and
    // effectively wave-uniform.
    float fwz[4], fwy[4], fwx[4];
    #pragma unroll
    for (int j = 0; j < 4; ++j) {
        fwz[j] = 0.0f; fwy[j] = 0.0f; fwx[j] = 0.0f;
        int x = xb + j;
        float g2z = (float)z + f2zv[j] * rf;
        float g2y = (float)y + f2yv[j] * rf;
        float g2x = (float)x + f2xv[j] * rf;
        float iz = ((g2z + 1.0f) * (float)DD - 1.0f) * 0.5f;
        float iy = ((g2y + 1.0f) * (float)HH - 1.0f) * 0.5f;
        float ix = ((g2x + 1.0f) * (float)WW - 1.0f) * 0.5f;
        if (ix > -1.0f && ix < (float)WW &&
            iy > -1.0f && iy < (float)HH &&
            iz > -1.0f && iz < (float)DD) {
            float zf = floorf(iz), yf = floorf(iy), xf = floorf(ix);
            int z0 = (int)zf, y0 = (int)yf, x0 = (int)xf;
            float tz = iz - zf, ty = iy - yf, tx = ix - xf;
            #pragma unroll
            for (int dz = 0; dz < 2; ++dz) {
                int zc = z0 + dz;
                if (zc < 0 || zc >= DD) continue;
                float wzc = dz ? tz : 1.0f - tz;
                #pragma unroll
                for (int dy = 0; dy < 2; ++dy) {
                    int yc = y0 + dy;
                    if (yc < 0 || yc >= HH) continue;
                    float wzy = wzc * (dy ? ty : 1.0f - ty);
                    #pragma unroll
                    for (int dx = 0; dx < 2; ++dx) {
                        int xc = x0 + dx;
                        if (xc < 0 || xc >= WW) continue;
                        float w = wzy * (dx ? tx : 1.0f - tx);
                        int off = (zc * HH + yc) * WW + xc;
                        fwz[j] += w * flow1[off];
                        fwy[j] += w * flow1[off + DHW];
                        fwx[j] += w * flow1[off + 2 * DHW];
                    }
                }
            }
        }
    }

    // ---- phase 2: addressing + weights for the second grid_sample.
    // The two x-corners are consecutive floats -> one 8B pair-load per
    // (dz,dy) row: 4 gather instructions per point instead of 8. Border
    // clamp is folded into the pair weights (wxa -> element at xbase,
    // wxb -> element at xbase+1).
    vfloat4 vofz, vofy, vofx;
    float wzw[4][2], wyw[4][2];
    float wxa[4], wxb[4];
    int   off[4][2][2];                   // float index of pair per (dz,dy)

    #pragma unroll
    for (int j = 0; j < 4; ++j) {
        int x = xb + j;
        float ofz = fwz[j] + f2zv[j];
        float ofy = fwy[j] + f2yv[j];
        float ofx = fwx[j] + f2xv[j];
        vofz[j] = ofz; vofy[j] = ofy; vofx[j] = ofx;

        float nz = (float)z + ofz * rf;
        float ny = (float)y + ofy * rf;
        float nx = (float)x + ofx * rf;
        float cz = 2.0f * (nz / (float)(DD - 1) - 0.5f);
        float cy = 2.0f * (ny / (float)(HH - 1) - 0.5f);
        float cx = 2.0f * (nx / (float)(WW - 1) - 0.5f);
        float sz2 = ((cz + 1.0f) * (float)DD - 1.0f) * 0.5f;
        float sy2 = ((cy + 1.0f) * (float)HH - 1.0f) * 0.5f;
        float sx2 = ((cx + 1.0f) * (float)WW - 1.0f) * 0.5f;

        float zf = floorf(sz2), yf = floorf(sy2), xf = floorf(sx2);
        int z0 = (int)zf, y0 = (int)yf, x0 = (int)xf;
        float tz = sz2 - zf, ty = sy2 - yf, tx = sx2 - xf;

        // z / y: zero OOB weights, clamp indices.
        float wzp[2] = {1.0f - tz, tz};
        float wyp[2] = {1.0f - ty, ty};
        int zi[2], yi[2];
        #pragma unroll
        for (int d = 0; d < 2; ++d) {
            int zc = z0 + d, yc = y0 + d;
            if (zc < 0 || zc >= DD) wzp[d] = 0.0f;
            if (yc < 0 || yc >= HH) wyp[d] = 0.0f;
            zi[d] = min(max(zc, 0), DD - 1);
            yi[d] = min(max(yc, 0), HH - 1);
        }
        wzw[j][0] = wzp[0]; wzw[j][1] = wzp[1];
        wyw[j][0] = wyp[0]; wyw[j][1] = wyp[1];

        // x: pair base clamped to [0, WW-2]; fold clamp into pair weights.
        float wx0 = 1.0f - tx, wx1 = tx;
        if (x0 < 0 || x0 >= WW)          wx0 = 0.0f;   // corner x0 OOB
        if (x0 + 1 < 0 || x0 + 1 >= WW)  wx1 = 0.0f;   // corner x0+1 OOB
        bool lo = (x0 < 0);
        bool hi = (x0 > WW - 2);
        int xbase = min(max(x0, 0), WW - 2);
        // element a = src[..+xbase], element b = src[..+xbase+1]
        wxa[j] = lo ? wx1 : (hi ? 0.0f : wx0);
        wxb[j] = hi ? wx0 : (lo ? 0.0f : wx1);

        #pragma unroll
        for (int dz = 0; dz < 2; ++dz)
            #pragma unroll
            for (int dy = 0; dy < 2; ++dy)
                off[j][dz][dy] = (zi[dz] * HH + yi[dy]) * WW + xbase;
    }

    // ---- phase 3: 16 independent pair-gathers back-to-back.
    vfloat2 v[4][4];
    #pragma unroll
    for (int j = 0; j < 4; ++j)
        #pragma unroll
        for (int dz = 0; dz < 2; ++dz)
            #pragma unroll
            for (int dy = 0; dy < 2; ++dy)
                v[j][dz * 2 + dy] = load_pair(src + off[j][dz][dy]);

    // ---- phase 4: combine + store.
    vfloat4 sval;
    #pragma unroll
    for (int j = 0; j < 4; ++j) {
        float acc = 0.0f;
        #pragma unroll
        for (int dz = 0; dz < 2; ++dz)
            #pragma unroll
            for (int dy = 0; dy < 2; ++dy) {
                float wzy = wzw[j][dz] * wyw[j][dy];
                vfloat2 p = v[j][dz * 2 + dy];
                acc = fmaf(wzy, fmaf(wxa[j], p.x, wxb[j] * p.y), acc);
            }
        sval[j] = acc;
    }

    // outputs: (deform [DHW], out_flow [3*DHW]); NT stores — never re-read.
    __builtin_nontemporal_store(sval, (vfloat4*)(out + idx0));
    __builtin_nontemporal_store(vofz, (vfloat4*)(out + DHW + idx0));
    __builtin_nontemporal_store(vofy, (vfloat4*)(out + 2 * DHW + idx0));
    __builtin_nontemporal_store(vofx, (vfloat4*)(out + 3 * DHW + idx0));
}

extern "C" void kernel_launch(void* const* d_in, const int* in_sizes, int n_in,
                              void* d_out, int out_size, void* d_ws, size_t ws_size,
                              hipStream_t stream) {
    const float* src   = (const float*)d_in[0];
    const float* flow1 = (const float*)d_in[1];
    const float* flow2 = (const float*)d_in[2];
    // d_in[3] is the meshgrid `grid` — deterministic, derived analytically.
    const float* prf   = (const float*)d_in[4];
    float* out = (float*)d_out;

    int threads_total = DHW / 4;
    int blocks = (threads_total + 255) / 256;   // 4800, divisible by 8
    st_fused_kernel<<<blocks, 256, 0, stream>>>(src, flow1, flow2, prf, out);
}